// Round 1
// baseline (1911.824 us; speedup 1.0000x reference)
//
#include <hip/hip_runtime.h>

#define BM 64
#define BN 64
#define BK 16
#define PAD 4

// C[m,h] = sum_d A[m,d] * W[h,d] + bias[h], accumulated in fp64.
template <typename PT>
__global__ __launch_bounds__(256) void gemm_nt(const float* __restrict__ A,
                                               const float* __restrict__ W,
                                               const float* __restrict__ bias,
                                               PT* __restrict__ C,
                                               int M, int D, int H) {
    __shared__ float As[BK][BM + PAD];
    __shared__ float Ws[BK][BN + PAD];
    const int tid = threadIdx.x;
    const int tx = tid & 15;        // 0..15 -> output col group
    const int ty = tid >> 4;        // 0..15 -> output row group
    const int row0 = blockIdx.x * BM;
    const int col0 = blockIdx.y * BN;
    const int lr = tid >> 2;        // 0..63 row within tile for loading
    const int lk = (tid & 3) << 2;  // 0,4,8,12 k-offset for loading

    double acc[4][4];
#pragma unroll
    for (int i = 0; i < 4; ++i)
#pragma unroll
        for (int j = 0; j < 4; ++j)
            acc[i][j] = (double)bias[col0 + tx * 4 + j];

    const float* Aptr = A + (size_t)(row0 + lr) * D + lk;
    const float* Wptr = W + (size_t)(col0 + lr) * D + lk;

    for (int kk = 0; kk < D; kk += BK) {
        float4 av = *reinterpret_cast<const float4*>(Aptr + kk);
        float4 wv = *reinterpret_cast<const float4*>(Wptr + kk);
        __syncthreads();
        As[lk + 0][lr] = av.x; As[lk + 1][lr] = av.y;
        As[lk + 2][lr] = av.z; As[lk + 3][lr] = av.w;
        Ws[lk + 0][lr] = wv.x; Ws[lk + 1][lr] = wv.y;
        Ws[lk + 2][lr] = wv.z; Ws[lk + 3][lr] = wv.w;
        __syncthreads();
#pragma unroll
        for (int k = 0; k < BK; ++k) {
            float a[4], w[4];
#pragma unroll
            for (int i = 0; i < 4; ++i) a[i] = As[k][ty * 4 + i];
#pragma unroll
            for (int j = 0; j < 4; ++j) w[j] = Ws[k][tx * 4 + j];
#pragma unroll
            for (int i = 0; i < 4; ++i)
#pragma unroll
                for (int j = 0; j < 4; ++j)
                    acc[i][j] += (double)a[i] * (double)w[j];
        }
    }
#pragma unroll
    for (int i = 0; i < 4; ++i) {
        size_t r = (size_t)(row0 + ty * 4 + i) * H + col0 + tx * 4;
#pragma unroll
        for (int j = 0; j < 4; ++j)
            C[r + j] = (PT)acc[i][j];
    }
}

// Serial LIF over t for each (b,h) chain: u = 0.5*u + I; s = (u>=0.5); u *= (1-s).
template <typename PT>
__global__ __launch_bounds__(256) void lif_scan(const PT* __restrict__ P,
                                                float* __restrict__ S,
                                                int B, int T, int H) {
    const int g = blockIdx.x * blockDim.x + threadIdx.x;
    if (g >= B * H) return;
    const int h = g & (H - 1);
    const int b = g / H;
    const size_t base = (size_t)b * T * H + h;
    double u = 0.0;
    for (int t0 = 0; t0 < T; t0 += 8) {
        double I[8];
#pragma unroll
        for (int j = 0; j < 8; ++j)
            I[j] = (double)P[base + (size_t)(t0 + j) * H];
#pragma unroll
        for (int j = 0; j < 8; ++j) {
            u = 0.5 * u + I[j];
            float s;
            if (u >= 0.5) { s = 1.0f; u = 0.0; } else { s = 0.0f; }
            S[base + (size_t)(t0 + j) * H] = s;
        }
    }
}

extern "C" void kernel_launch(void* const* d_in, const int* in_sizes, int n_in,
                              void* d_out, int out_size, void* d_ws, size_t ws_size,
                              hipStream_t stream) {
    const float* x  = (const float*)d_in[0];  // [32, 512, 512]
    const float* W0 = (const float*)d_in[1];  // [1024, 512]
    const float* b0 = (const float*)d_in[2];  // [1024]
    const float* W1 = (const float*)d_in[3];  // [1024, 1024]
    const float* b1 = (const float*)d_in[4];
    const float* W2 = (const float*)d_in[5];  // [1024, 1024]
    const float* b2 = (const float*)d_in[6];

    const int B = 32, T = 512, D0 = 512, H = 1024;
    const int M = B * T;  // 16384

    float* S = (float*)d_out;  // spike buffer, reused across layers; final output

    dim3 gemm_grid(M / BM, H / BN);  // 256 x 16
    const int scan_blocks = (B * H) / 256;  // 128

    const bool use_f64 = ws_size >= (size_t)M * H * sizeof(double);

    if (use_f64) {
        double* P = (double*)d_ws;
        gemm_nt<double><<<gemm_grid, 256, 0, stream>>>(x, W0, b0, P, M, D0, H);
        lif_scan<double><<<scan_blocks, 256, 0, stream>>>(P, S, B, T, H);
        gemm_nt<double><<<gemm_grid, 256, 0, stream>>>(S, W1, b1, P, M, H, H);
        lif_scan<double><<<scan_blocks, 256, 0, stream>>>(P, S, B, T, H);
        gemm_nt<double><<<gemm_grid, 256, 0, stream>>>(S, W2, b2, P, M, H, H);
        lif_scan<double><<<scan_blocks, 256, 0, stream>>>(P, S, B, T, H);
    } else {
        float* P = (float*)d_ws;
        gemm_nt<float><<<gemm_grid, 256, 0, stream>>>(x, W0, b0, P, M, D0, H);
        lif_scan<float><<<scan_blocks, 256, 0, stream>>>(P, S, B, T, H);
        gemm_nt<float><<<gemm_grid, 256, 0, stream>>>(S, W1, b1, P, M, H, H);
        lif_scan<float><<<scan_blocks, 256, 0, stream>>>(P, S, B, T, H);
        gemm_nt<float><<<gemm_grid, 256, 0, stream>>>(S, W2, b2, P, M, H, H);
        lif_scan<float><<<scan_blocks, 256, 0, stream>>>(P, S, B, T, H);
    }
}

// Round 2
// 1070.087 us; speedup vs baseline: 1.7866x; 1.7866x over previous
//
#include <hip/hip_runtime.h>

#define BM 64
#define BN 64
#define BK 16
#define PAD 4

// Dense: C[m,h] = sum_d A[m,d] * W[h,d] + bias[h], accumulated in fp64.
template <typename PT>
__global__ __launch_bounds__(256) void gemm_nt(const float* __restrict__ A,
                                               const float* __restrict__ W,
                                               const float* __restrict__ bias,
                                               PT* __restrict__ C,
                                               int M, int D, int H) {
    __shared__ float As[BK][BM + PAD];
    __shared__ float Ws[BK][BN + PAD];
    const int tid = threadIdx.x;
    const int tx = tid & 15;
    const int ty = tid >> 4;
    const int row0 = blockIdx.x * BM;
    const int col0 = blockIdx.y * BN;
    const int lr = tid >> 2;
    const int lk = (tid & 3) << 2;

    double acc[4][4];
#pragma unroll
    for (int i = 0; i < 4; ++i)
#pragma unroll
        for (int j = 0; j < 4; ++j)
            acc[i][j] = (double)bias[col0 + tx * 4 + j];

    const float* Aptr = A + (size_t)(row0 + lr) * D + lk;
    const float* Wptr = W + (size_t)(col0 + lr) * D + lk;

    for (int kk = 0; kk < D; kk += BK) {
        float4 av = *reinterpret_cast<const float4*>(Aptr + kk);
        float4 wv = *reinterpret_cast<const float4*>(Wptr + kk);
        __syncthreads();
        As[lk + 0][lr] = av.x; As[lk + 1][lr] = av.y;
        As[lk + 2][lr] = av.z; As[lk + 3][lr] = av.w;
        Ws[lk + 0][lr] = wv.x; Ws[lk + 1][lr] = wv.y;
        Ws[lk + 2][lr] = wv.z; Ws[lk + 3][lr] = wv.w;
        __syncthreads();
#pragma unroll
        for (int k = 0; k < BK; ++k) {
            float a[4], w[4];
#pragma unroll
            for (int i = 0; i < 4; ++i) a[i] = As[k][ty * 4 + i];
#pragma unroll
            for (int j = 0; j < 4; ++j) w[j] = Ws[k][tx * 4 + j];
#pragma unroll
            for (int i = 0; i < 4; ++i)
#pragma unroll
                for (int j = 0; j < 4; ++j)
                    acc[i][j] += (double)a[i] * (double)w[j];
        }
    }
#pragma unroll
    for (int i = 0; i < 4; ++i) {
        size_t r = (size_t)(row0 + ty * 4 + i) * H + col0 + tx * 4;
#pragma unroll
        for (int j = 0; j < 4; ++j)
            C[r + j] = (PT)acc[i][j];
    }
}

// 1024x1024 transpose: Wt[d][h] = W[h][d]
__global__ __launch_bounds__(256) void transpose_w(const float* __restrict__ W,
                                                   float* __restrict__ Wt) {
    __shared__ float t[32][33];
    const int N = 1024;
    const int bx = blockIdx.x * 32, by = blockIdx.y * 32;
    int x = bx + threadIdx.x;
    int y = by + threadIdx.y;
#pragma unroll
    for (int j = 0; j < 32; j += 8)
        t[threadIdx.y + j][threadIdx.x] = W[(size_t)(y + j) * N + x];
    __syncthreads();
    x = by + threadIdx.x;
    y = bx + threadIdx.y;
#pragma unroll
    for (int j = 0; j < 32; j += 8)
        Wt[(size_t)(y + j) * N + x] = t[threadIdx.x][threadIdx.y + j];
}

// Sparse spike-driven layer: P[m,h] = bias[h] + sum_{d: S[m,d]!=0} Wt[d][h]
// 8 rows per block; union active-list with 8-bit row masks; fp64 accumulation.
__global__ __launch_bounds__(256) void spike_gemm(const float* __restrict__ S,
                                                  const float* __restrict__ Wt,
                                                  const float* __restrict__ bias,
                                                  double* __restrict__ P) {
    __shared__ int idx[1024];
    __shared__ int cnts[4];
    const int tid = threadIdx.x;
    const int wave = tid >> 6;
    const int lane = tid & 63;
    const int m0 = blockIdx.x * 8;

    // Phase 1: per-wave deterministic ballot compaction over d in [wave*256, wave*256+256)
    int base = 0;
#pragma unroll
    for (int jj = 0; jj < 4; ++jj) {
        const int d = wave * 256 + jj * 64 + lane;
        unsigned mask8 = 0;
#pragma unroll
        for (int r = 0; r < 8; ++r) {
            float s = S[(size_t)(m0 + r) * 1024 + d];
            mask8 |= (s != 0.0f) ? (1u << r) : 0u;
        }
        unsigned long long b = __ballot(mask8 != 0);
        int pos = __popcll(b & ((1ull << lane) - 1ull));
        if (mask8) idx[wave * 256 + base + pos] = d | (int)(mask8 << 16);
        base += __popcll(b);
    }
    if (lane == 0) cnts[wave] = base;
    __syncthreads();

    // Phase 2: accumulate in fp64
    const int h0 = tid * 4;
    double acc[8][4];
    {
        double bv[4];
#pragma unroll
        for (int j = 0; j < 4; ++j) bv[j] = (double)bias[h0 + j];
#pragma unroll
        for (int r = 0; r < 8; ++r)
#pragma unroll
            for (int j = 0; j < 4; ++j) acc[r][j] = bv[j];
    }

    for (int s = 0; s < 4; ++s) {
        const int cnt = cnts[s];
        if (cnt == 0) continue;
        const int* seg = idx + s * 256;
        // 1-deep pipeline
        int e0 = seg[0];
        int d = __builtin_amdgcn_readfirstlane(e0) & 0x3FF;
        unsigned msk = ((unsigned)__builtin_amdgcn_readfirstlane(e0)) >> 16;
        float4 wv = *reinterpret_cast<const float4*>(Wt + ((size_t)d << 10) + h0);
        for (int i = 0; i < cnt; ++i) {
            float4 cw = wv;
            unsigned cm = msk;
            if (i + 1 < cnt) {
                int e = seg[i + 1];
                d = __builtin_amdgcn_readfirstlane(e) & 0x3FF;
                msk = ((unsigned)__builtin_amdgcn_readfirstlane(e)) >> 16;
                wv = *reinterpret_cast<const float4*>(Wt + ((size_t)d << 10) + h0);
            }
            const double w0 = (double)cw.x, w1 = (double)cw.y,
                         w2 = (double)cw.z, w3 = (double)cw.w;
#pragma unroll
            for (int r = 0; r < 8; ++r) {
                if (cm & (1u << r)) {
                    acc[r][0] += w0; acc[r][1] += w1;
                    acc[r][2] += w2; acc[r][3] += w3;
                }
            }
        }
    }

    // Phase 3: write P
#pragma unroll
    for (int r = 0; r < 8; ++r) {
        double* p = P + (size_t)(m0 + r) * 1024 + h0;
        p[0] = acc[r][0]; p[1] = acc[r][1]; p[2] = acc[r][2]; p[3] = acc[r][3];
    }
}

// Serial LIF over t for each (b,h) chain.
template <typename PT>
__global__ __launch_bounds__(256) void lif_scan(const PT* __restrict__ P,
                                                float* __restrict__ S,
                                                int B, int T, int H) {
    const int g = blockIdx.x * blockDim.x + threadIdx.x;
    if (g >= B * H) return;
    const int h = g & (H - 1);
    const int b = g / H;
    const size_t base = (size_t)b * T * H + h;
    double u = 0.0;
    for (int t0 = 0; t0 < T; t0 += 8) {
        double I[8];
#pragma unroll
        for (int j = 0; j < 8; ++j)
            I[j] = (double)P[base + (size_t)(t0 + j) * H];
#pragma unroll
        for (int j = 0; j < 8; ++j) {
            u = 0.5 * u + I[j];
            float s;
            if (u >= 0.5) { s = 1.0f; u = 0.0; } else { s = 0.0f; }
            S[base + (size_t)(t0 + j) * H] = s;
        }
    }
}

extern "C" void kernel_launch(void* const* d_in, const int* in_sizes, int n_in,
                              void* d_out, int out_size, void* d_ws, size_t ws_size,
                              hipStream_t stream) {
    const float* x  = (const float*)d_in[0];
    const float* W0 = (const float*)d_in[1];
    const float* b0 = (const float*)d_in[2];
    const float* W1 = (const float*)d_in[3];
    const float* b1 = (const float*)d_in[4];
    const float* W2 = (const float*)d_in[5];
    const float* b2 = (const float*)d_in[6];

    const int B = 32, T = 512, D0 = 512, H = 1024;
    const int M = B * T;  // 16384

    float* S = (float*)d_out;

    dim3 gemm_grid(M / BM, H / BN);
    const int scan_blocks = (B * H) / 256;

    const size_t P_bytes = (size_t)M * H * sizeof(double);      // 2^27
    const size_t need_sparse = P_bytes + (size_t)H * H * 4;     // + 4 MB Wt

    if (ws_size >= need_sparse) {
        double* P = (double*)d_ws;
        float* Wt = (float*)((char*)d_ws + P_bytes);
        dim3 tgrid(H / 32, H / 32);
        dim3 tblk(32, 8);

        // Layer 0: dense fp64 GEMM (real-valued input)
        gemm_nt<double><<<gemm_grid, 256, 0, stream>>>(x, W0, b0, P, M, D0, H);
        lif_scan<double><<<scan_blocks, 256, 0, stream>>>(P, S, B, T, H);

        // Layer 1: sparse (binary spikes)
        transpose_w<<<tgrid, tblk, 0, stream>>>(W1, Wt);
        spike_gemm<<<M / 8, 256, 0, stream>>>(S, Wt, b1, P);
        lif_scan<double><<<scan_blocks, 256, 0, stream>>>(P, S, B, T, H);

        // Layer 2: sparse
        transpose_w<<<tgrid, tblk, 0, stream>>>(W2, Wt);
        spike_gemm<<<M / 8, 256, 0, stream>>>(S, Wt, b2, P);
        lif_scan<double><<<scan_blocks, 256, 0, stream>>>(P, S, B, T, H);
    } else if (ws_size >= P_bytes) {
        double* P = (double*)d_ws;
        gemm_nt<double><<<gemm_grid, 256, 0, stream>>>(x, W0, b0, P, M, D0, H);
        lif_scan<double><<<scan_blocks, 256, 0, stream>>>(P, S, B, T, H);
        gemm_nt<double><<<gemm_grid, 256, 0, stream>>>(S, W1, b1, P, M, H, H);
        lif_scan<double><<<scan_blocks, 256, 0, stream>>>(P, S, B, T, H);
        gemm_nt<double><<<gemm_grid, 256, 0, stream>>>(S, W2, b2, P, M, H, H);
        lif_scan<double><<<scan_blocks, 256, 0, stream>>>(P, S, B, T, H);
    } else {
        float* P = (float*)d_ws;
        gemm_nt<float><<<gemm_grid, 256, 0, stream>>>(x, W0, b0, P, M, D0, H);
        lif_scan<float><<<scan_blocks, 256, 0, stream>>>(P, S, B, T, H);
        gemm_nt<float><<<gemm_grid, 256, 0, stream>>>(S, W1, b1, P, M, H, H);
        lif_scan<float><<<scan_blocks, 256, 0, stream>>>(P, S, B, T, H);
        gemm_nt<float><<<gemm_grid, 256, 0, stream>>>(S, W2, b2, P, M, H, H);
        lif_scan<float><<<scan_blocks, 256, 0, stream>>>(P, S, B, T, H);
    }
}